// Round 7
// baseline (153.339 us; speedup 1.0000x reference)
//
#include <hip/hip_runtime.h>
#include <stdint.h>

#define NGT_MAX 128
#define CAND_CAP 8192
#define RANK_CAP 2048
#define FILT_CAP 16384
#define SUB_CAP 2048

// counters: [0]=cand cnt, [1]=M1, [2]=M2, [4]=fg filt, [5]=bg filt,
//           [8]=needF, [9]=needB, [10]=Tf, [11]=Tb, [12]=kbg  (1,2,8..12 published by k_gather b0)

// ---- threefry2x32 (exact JAX semantics) ----
__host__ __device__ inline void tf2x32(uint32_t k0, uint32_t k1, uint32_t c0, uint32_t c1,
                                       uint32_t& o0, uint32_t& o1) {
  uint32_t ks[3] = {k0, k1, k0 ^ k1 ^ 0x1BD11BDAu};
  uint32_t x0 = c0 + ks[0];
  uint32_t x1 = c1 + ks[1];
  const int rot[2][4] = {{13, 15, 26, 6}, {17, 29, 16, 24}};
#pragma unroll
  for (int i = 0; i < 5; ++i) {
#pragma unroll
    for (int j = 0; j < 4; ++j) {
      x0 += x1;
      int r = rot[i & 1][j];
      x1 = (x1 << r) | (x1 >> (32 - r));
      x1 ^= x0;
    }
    x0 += ks[(i + 1) % 3];
    x1 += ks[(i + 2) % 3] + (uint32_t)(i + 1);
  }
  o0 = x0; o1 = x1;
}

// Partitionable threefry: element i uses block (0,i); draw = o0^o1.
// Selection key = (bits>>9, index) lexicographic (stable argsort tiebreak).
__device__ inline uint64_t sel_key(uint32_t i, uint32_t ka, uint32_t kb) {
  uint32_t o0, o1;
  tf2x32(ka, kb, 0u, i, o0, o1);
  uint32_t bits = o0 ^ o1;
  return ((uint64_t)(bits >> 9) << 32) | (uint64_t)i;
}

__device__ inline uint32_t fmap(float v) {
  uint32_t u = __float_as_uint(v);
  return (u & 0x80000000u) ? ~u : (u | 0x80000000u);
}
__device__ inline float funmap(uint32_t m) {
  return (m & 0x80000000u) ? __uint_as_float(m & 0x7FFFFFFFu) : __uint_as_float(~m);
}

// Single IoU pass (half-grid; bOff selects the half). Identical math to R6.
__global__ void __launch_bounds__(256)
k_main(const float4* __restrict__ anc, const float* __restrict__ img,
       const float4* __restrict__ gt, int N, int R, int bOff,
       uint32_t* __restrict__ pmax, uint32_t* __restrict__ gmaxu,
       float* __restrict__ LBL, float4* __restrict__ TGT,
       uint32_t* __restrict__ pmeta) {
  __shared__ float4 sgt[NGT_MAX];
  __shared__ float sarea[NGT_MAX];
  __shared__ float sq[64 * 101];
  __shared__ uint32_t scnt[2];
  const int t = threadIdx.x;
  const int b = blockIdx.x + bOff;
  if (t < 2) scnt[t] = 0u;
  if (t < R) {
    float4 g = gt[t];
    sgt[t] = g;
    {
#pragma clang fp contract(off)
      sarea[t] = (g.z - g.x + 1.0f) * (g.w - g.y + 1.0f);
    }
  }
  __syncthreads();
  const int lane = t & 63, lm = t & 3, q = t >> 2;
  const int i = b * 256 + t;
  const float H = img[0], W = img[1];
  float4 a = anc[i];
  bool inside = (a.x >= 0.0f) && (a.y >= 0.0f) && (a.z < W) && (a.w < H);
  float area_a;
  {
#pragma clang fp contract(off)
    area_a = (a.z - a.x + 1.0f) * (a.w - a.y + 1.0f);
  }
  if (!inside) area_a = __uint_as_float(0x7FC00000u);  // NaN-poison; v_max discards NaN
  const bool b1 = (lm == 1), b2 = (lm == 2), b3 = (lm == 3);
  float part[25];
  float vmax = -1.0f;
#pragma unroll
  for (int s = 0; s < 25; ++s) {
    const int gb0 = 4 * s;
    if (gb0 >= R) break;
    float v2q[4];
#pragma unroll
    for (int k = 0; k < 4; ++k) {
      const int g = gb0 + k;
      if (g < R) {
        float4 gb = sgt[g];
        float v;
        {
#pragma clang fp contract(off)
          float iw = fminf(a.z, gb.z) - fmaxf(a.x, gb.x) + 1.0f;
          float ih = fminf(a.w, gb.w) - fmaxf(a.y, gb.y) + 1.0f;
          float inter = fmaxf(iw, 0.0f) * fmaxf(ih, 0.0f);
          v = inter / (area_a + sarea[g] - inter);
        }
        vmax = fmaxf(vmax, v);
        int s1 = __builtin_amdgcn_mov_dpp(__float_as_int(v), 0xB1, 0xF, 0xF, true);
        float v1 = fmaxf(v, __int_as_float(s1));
        int s2 = __builtin_amdgcn_mov_dpp(__float_as_int(v1), 0x4E, 0xF, 0xF, true);
        v2q[k] = fmaxf(v1, __int_as_float(s2));
      } else {
        v2q[k] = -1.0f;
      }
    }
    float p = v2q[0];
    p = b1 ? v2q[1] : p;
    p = b2 ? v2q[2] : p;
    p = b3 ? v2q[3] : p;
    part[s] = p;
  }
  float lbl = -1.0f;
  if (inside) {
    if (vmax < 0.3f) lbl = 0.0f;
    if (vmax >= 0.7f) lbl = 1.0f;
  }
  LBL[i] = lbl;
  unsigned long long bf = __ballot(lbl == 1.0f);
  unsigned long long bb = __ballot(lbl == 0.0f);
  if (lane == 0) {
    atomicAdd(&scnt[0], (uint32_t)__popcll(bf));
    atomicAdd(&scnt[1], (uint32_t)__popcll(bb));
  }
  float4 o = make_float4(0.f, 0.f, 0.f, 0.f);
  if (inside) {
    int idx = (int)vmax;  // faithful astype(int32) of max_ov
    idx = idx < 0 ? 0 : idx;
    idx = idx > R - 1 ? R - 1 : idx;
    float4 gb = sgt[idx];
    {
#pragma clang fp contract(off)
      float aw = a.z - a.x + 1.0f;
      float ah = a.w - a.y + 1.0f;
      float acx = a.x + 0.5f * aw;
      float acy = a.y + 0.5f * ah;
      float gw = gb.z - gb.x + 1.0f;
      float gh = gb.w - gb.y + 1.0f;
      float gcx = gb.x + 0.5f * gw;
      float gcy = gb.y + 0.5f * gh;
      o.x = (gcx - acx) / aw;
      o.y = (gcy - acy) / ah;
      o.z = logf(gw / aw);
      o.w = logf(gh / ah);
    }
  }
  TGT[i] = o;
#pragma unroll
  for (int s = 0; s < 25; ++s) {
    const int g = 4 * s + lm;
    if (4 * s >= R) break;
    if (g < R) sq[q * 101 + g] = part[s];
  }
  __syncthreads();
  if (t < R) {
    float m = -1.0f;
#pragma unroll 8
    for (int k2 = 0; k2 < 64; ++k2) m = fmaxf(m, sq[k2 * 101 + t]);
    uint32_t u = fmap(m);
    pmax[b * R + t] = u;
    if (u > gmaxu[t]) atomicMax(&gmaxu[t], u);  // stale-high skip safe (monotone)
  }
  if (t == 0) pmeta[b] = scnt[0] | (scnt[1] << 16);
}

// Tie-set candidates + snapshot of their pre-flip labels. Block-staged append.
__global__ void __launch_bounds__(256)
k_cand(const float4* __restrict__ anc, const float* __restrict__ img,
       const float4* __restrict__ gt, int N, int R,
       const uint32_t* __restrict__ pmax, const uint32_t* __restrict__ gmaxu,
       const float* __restrict__ LBL,
       uint64_t* __restrict__ candList, uint32_t* __restrict__ candLbl,
       uint32_t* __restrict__ counters, uint32_t ka, uint32_t kb) {
  __shared__ int tg[NGT_MAX];
  __shared__ float tgm[NGT_MAX];
  __shared__ uint64_t buf[256];
  __shared__ uint32_t bufL[256];
  __shared__ uint32_t bcnt, bbase;
  __shared__ int tcnt;
  const int t = threadIdx.x, b = blockIdx.x;
  if (t == 0) { tcnt = 0; bcnt = 0u; }
  __syncthreads();
  if (t < R) {
    uint32_t pm = pmax[b * R + t];
    uint32_t gm = gmaxu[t];
    if (pm == gm) { int p = atomicAdd(&tcnt, 1); tg[p] = t; tgm[p] = funmap(gm); }
  }
  __syncthreads();
  const int C0 = tcnt;
  if (C0 == 0) return;
  const int i = b * 256 + t;
  const float H = img[0], W = img[1];
  float4 a = anc[i];
  bool inside = (a.x >= 0.0f) && (a.y >= 0.0f) && (a.z < W) && (a.w < H);
  if (inside) {
    float area_a;
    {
#pragma clang fp contract(off)
      area_a = (a.z - a.x + 1.0f) * (a.w - a.y + 1.0f);
    }
    bool cand = false;
    for (int j = 0; j < C0; ++j) {
      float4 gb = gt[tg[j]];
      float v;
      {
#pragma clang fp contract(off)
        float ag = (gb.z - gb.x + 1.0f) * (gb.w - gb.y + 1.0f);
        float iw = fminf(a.z, gb.z) - fmaxf(a.x, gb.x) + 1.0f;
        float ih = fminf(a.w, gb.w) - fmaxf(a.y, gb.y) + 1.0f;
        float inter = fmaxf(iw, 0.0f) * fmaxf(ih, 0.0f);
        v = inter / (area_a + ag - inter);
      }
      cand = cand || (v == tgm[j]);
    }
    if (cand) {
      float old = LBL[i];
      uint32_t code = (old == 1.0f) ? 2u : ((old == 0.0f) ? 1u : 0u);
      uint32_t p = atomicAdd(&bcnt, 1u);
      buf[p] = sel_key((uint32_t)i, ka, kb);
      bufL[p] = code;
    }
  }
  __syncthreads();
  if (t == 0 && bcnt) bbase = atomicAdd(&counters[0], bcnt);
  __syncthreads();
  for (uint32_t j = t; j < bcnt; j += 256) {
    uint32_t p = bbase + j;
    if (p < CAND_CAP) { candList[p] = buf[j]; candLbl[p] = bufL[j]; }
  }
}

// Merged meta+gather: each block independently computes M1/M2, the kept-cand set
// (rank<R), thresholds; applies flips for its own anchors; prefilters and block-stage
// appends fg/bg survivors. Block 0 publishes meta for k_sel. All inputs read-only.
__global__ void __launch_bounds__(256)
k_gather(float* __restrict__ LBL, int N, int NB, int R,
         const uint64_t* __restrict__ candList, const uint32_t* __restrict__ candLbl,
         const uint32_t* __restrict__ pmeta,
         uint64_t* __restrict__ listF, uint64_t* __restrict__ listB,
         uint32_t* __restrict__ counters,
         uint32_t k2a, uint32_t k2b, uint32_t k3a, uint32_t k3b) {
  __shared__ uint64_t sub[RANK_CAP];     // 16 KB
  __shared__ uint64_t red[256];          // 2 KB
  __shared__ uint64_t bufF[256], bufB[256];
  __shared__ uint32_t sflag[256];
  __shared__ uint32_t sdFB[2];
  __shared__ uint32_t smeta[6];  // 0 needF,1 needB,2 Tf,3 Tb,4 M1,5 M2
  __shared__ uint32_t cF, cB, oF, oB;
  const int t = threadIdx.x, b = blockIdx.x;
  sflag[t] = 0u;
  if (t < 2) sdFB[t] = 0u;
  if (t == 0) { cF = 0u; cB = 0u; }
  // pmeta sum -> baseF/baseB
  uint64_t sm = 0;
  for (int j = t; j < NB; j += 256) {
    uint32_t v = pmeta[j];
    sm += (uint64_t)(v & 0xFFFFu) | ((uint64_t)(v >> 16) << 32);
  }
  red[t] = sm;
  uint32_t C = counters[0];
  if (C > RANK_CAP) C = RANK_CAP;
  __syncthreads();
  for (int s = 128; s > 0; s >>= 1) {
    if (t < s) red[t] += red[t + s];
    __syncthreads();
  }
  const uint32_t baseF = (uint32_t)(red[0] & 0xFFFFFFFFu);
  const uint32_t baseB = (uint32_t)(red[0] >> 32);
  // kept-cand set: rank-select k smallest among C
  for (uint32_t s = t; s < C; s += 256) sub[s] = candList[s];
  __syncthreads();
  for (uint32_t e = t; e < C; e += 256) {
    uint64_t key = sub[e];
    bool keep = true;
    if (C > (uint32_t)R) {
      uint32_t rank = 0;
      for (uint32_t j = 0; j < C; ++j) rank += (sub[j] < key) ? 1u : 0u;
      keep = (rank < (uint32_t)R);
    }
    if (keep) {
      uint32_t code = candLbl[e];
      if (code != 2u) atomicAdd(&sdFB[0], 1u);
      if (code == 1u) atomicAdd(&sdFB[1], 1u);
      uint32_t idx = (uint32_t)key;
      if ((int)(idx >> 8) == b) sflag[idx & 255u] = 1u;
    }
  }
  __syncthreads();
  if (t == 0) {
    uint32_t M1 = baseF + sdFB[0];
    uint32_t M2 = baseB - sdFB[1];
    uint32_t nfg = M1 < 128u ? M1 : 128u;
    uint32_t kbg = 256u - nfg;
    uint32_t needF = (M1 > 128u) ? 1u : 0u;
    uint32_t needB = (M2 > kbg) ? 1u : 0u;
    uint64_t Tf = 0, Tb = 0;
    if (needF) {
      Tf = (((uint64_t)(128u * 32u)) << 23) / (uint64_t)M1;
      if (Tf > (1u << 23)) Tf = (1u << 23);
    }
    if (needB) {
      Tb = (((uint64_t)(kbg * 32u)) << 23) / (uint64_t)M2;
      if (Tb > (1u << 23)) Tb = (1u << 23);
    }
    smeta[0] = needF; smeta[1] = needB; smeta[2] = (uint32_t)Tf; smeta[3] = (uint32_t)Tb;
    smeta[4] = M1; smeta[5] = M2;
    if (b == 0) {
      counters[1] = M1; counters[2] = M2;
      counters[8] = needF; counters[9] = needB;
      counters[10] = (uint32_t)Tf; counters[11] = (uint32_t)Tb;
      counters[12] = kbg;
    }
  }
  __syncthreads();
  const uint32_t needF = smeta[0], needB = smeta[1], Tf = smeta[2], Tb = smeta[3];
  const int i = b * 256 + t;
  float old = LBL[i];
  float l1 = sflag[t] ? 1.0f : old;
  float out = l1;
  if (l1 == 1.0f) {
    if (needF) {
      uint64_t key = sel_key((uint32_t)i, k2a, k2b);
      if ((uint32_t)(key >> 32) >= Tf) {
        out = -1.0f;  // provably not among the k smallest
      } else {
        uint32_t p = atomicAdd(&cF, 1u);
        bufF[p] = key;
      }
    }
  } else if (l1 == 0.0f) {
    if (needB) {
      uint64_t key = sel_key((uint32_t)i, k3a, k3b);
      if ((uint32_t)(key >> 32) >= Tb) {
        out = -1.0f;
      } else {
        uint32_t p = atomicAdd(&cB, 1u);
        bufB[p] = key;
      }
    }
  }
  LBL[i] = out;
  __syncthreads();
  if (t == 0 && cF) oF = atomicAdd(&counters[4], cF);
  if (t == 64 && cB) oB = atomicAdd(&counters[5], cB);
  __syncthreads();
  for (uint32_t j = t; j < cF; j += 256) {
    uint32_t p = oF + j;
    if (p < FILT_CAP) listF[p] = bufF[j];
  }
  for (uint32_t j = t; j < cB; j += 256) {
    uint32_t p = oB + j;
    if (p < FILT_CAP) listB[p] = bufB[j];
  }
}

// exact k-smallest among filtered list (all keys < T): 256-bin hist + scan + in-bin rank.
__device__ __forceinline__ void do_select(const uint64_t* list, uint32_t Mf, uint32_t k,
                                          uint32_t T, float* LBL, uint32_t* h,
                                          uint32_t* c0, uint32_t* c1, uint64_t* sub,
                                          uint32_t* scal) {
  const int t = threadIdx.x;
  if (Mf <= k) return;  // keep all (uniform)
  int bl = (T > 1u) ? (32 - __clz(T - 1u)) : 0;
  int shift = bl > 8 ? bl - 8 : 0;
  h[t] = 0u;
  if (t == 0) { scal[0] = 0u; scal[1] = 0u; scal[2] = 0u; }
  __syncthreads();
  for (uint32_t j = t; j < Mf; j += 256)
    atomicAdd(&h[((uint32_t)(list[j] >> 32)) >> shift], 1u);
  __syncthreads();
  c0[t] = h[t];
  __syncthreads();
  uint32_t* s = c0;
  uint32_t* d = c1;
  for (int dd = 1; dd < 256; dd <<= 1) {
    uint32_t v = s[t];
    if (t >= dd) v += s[t - dd];
    d[t] = v;
    __syncthreads();
    uint32_t* tmp = s; s = d; d = tmp;
  }
  uint32_t inc = s[t];
  uint32_t exc = inc - h[t];
  if (exc < k && inc >= k) { scal[1] = (uint32_t)t; scal[2] = k - exc; }
  __syncthreads();
  const uint32_t binb = scal[1], rneed = scal[2];
  for (uint32_t j = t; j < Mf; j += 256) {
    uint64_t key = list[j];
    uint32_t bin = ((uint32_t)(key >> 32)) >> shift;
    if (bin > binb) {
      LBL[(uint32_t)key] = -1.0f;
    } else if (bin == binb) {
      uint32_t p = atomicAdd(&scal[0], 1u);
      if (p < SUB_CAP) sub[p] = key;
    }
  }
  __syncthreads();
  uint32_t c = scal[0] < SUB_CAP ? scal[0] : SUB_CAP;
  for (uint32_t s2 = t; s2 < c; s2 += 256) {
    uint64_t key = sub[s2];
    uint32_t rank = 0u;
    for (uint32_t j = 0; j < c; ++j) rank += (sub[j] < key) ? 1u : 0u;
    if (rank >= rneed) LBL[(uint32_t)key] = -1.0f;
  }
  __syncthreads();
}

__global__ void __launch_bounds__(256)
k_sel(float* __restrict__ LBL, const uint64_t* __restrict__ listF,
      const uint64_t* __restrict__ listB, uint32_t* __restrict__ counters) {
  __shared__ uint32_t h[256], c0[256], c1[256];
  __shared__ uint64_t sub[SUB_CAP];
  __shared__ uint32_t scal[4];
  if (counters[8]) {
    uint32_t Mf = counters[4];
    if (Mf > FILT_CAP) Mf = FILT_CAP;
    do_select(listF, Mf, 128u, counters[10], LBL, h, c0, c1, sub, scal);
  }
  if (counters[9]) {
    uint32_t Mf = counters[5];
    if (Mf > FILT_CAP) Mf = FILT_CAP;
    do_select(listB, Mf, counters[12], counters[11], LBL, h, c0, c1, sub, scal);
  }
}

extern "C" void kernel_launch(void* const* d_in, const int* in_sizes, int n_in,
                              void* d_out, int out_size, void* d_ws, size_t ws_size,
                              hipStream_t stream) {
  (void)n_in; (void)out_size; (void)ws_size;
  const int N = in_sizes[0] / 4;  // 262144 anchors (multiple of 512)
  const int R = in_sizes[2] / 4;  // 100 gt boxes
  const int NB = N / 256;
  const float4* anc = (const float4*)d_in[0];
  const float* img = (const float*)d_in[1];
  const float4* gtb = (const float4*)d_in[2];
  float* LBL = (float*)d_out;
  float4* TGT = (float4*)((float*)d_out + N);

  uint8_t* ws = (uint8_t*)d_ws;
  uint32_t* counters = (uint32_t*)ws;                  // 16 u32 @ 0
  uint32_t* gmaxu = (uint32_t*)(ws + 512);             // 128 u32 @ 512
  uint32_t* pmeta = (uint32_t*)(ws + 1024);            // NB u32 @ 1024
  uint32_t* candLbl = (uint32_t*)(ws + 1024 + 4096);   // CAND_CAP u32
  uint32_t* pmax = (uint32_t*)(ws + 65536);            // NB*R u32 (~410 KB)
  size_t off = 65536 + (size_t)NB * R * 4;
  off = (off + 7) & ~(size_t)7;
  uint64_t* candList = (uint64_t*)(ws + off);
  uint64_t* listF = (uint64_t*)(ws + off + CAND_CAP * 8);
  uint64_t* listB = (uint64_t*)(ws + off + CAND_CAP * 8 + FILT_CAP * 8);

  // Partitionable jax.random.split(key(42), 3): key_j = threefry((0,42),(0,j))
  uint32_t k1a, k1b, k2a, k2b, k3a, k3b;
  tf2x32(0u, 42u, 0u, 0u, k1a, k1b);
  tf2x32(0u, 42u, 0u, 1u, k2a, k2b);
  tf2x32(0u, 42u, 0u, 2u, k3a, k3b);

  hipMemsetAsync(ws, 0, 1024, stream);  // counters + gmaxu
  k_main<<<NB / 2, 256, 0, stream>>>(anc, img, gtb, N, R, 0, pmax, gmaxu, LBL, TGT, pmeta);
  k_main<<<NB / 2, 256, 0, stream>>>(anc, img, gtb, N, R, NB / 2, pmax, gmaxu, LBL, TGT,
                                     pmeta);
  k_cand<<<NB, 256, 0, stream>>>(anc, img, gtb, N, R, pmax, gmaxu, LBL, candList, candLbl,
                                 counters, k1a, k1b);
  k_gather<<<NB, 256, 0, stream>>>(LBL, N, NB, R, candList, candLbl, pmeta, listF, listB,
                                   counters, k2a, k2b, k3a, k3b);
  k_sel<<<1, 256, 0, stream>>>(LBL, listF, listB, counters);
}

// Round 8
// 143.508 us; speedup vs baseline: 1.0685x; 1.0685x over previous
//
#include <hip/hip_runtime.h>
#include <stdint.h>

#define NGT_MAX 128
#define CAND_CAP 8192
#define RANK_CAP 2048
#define FILT_CAP 16384
#define SUB_CAP 2048

// counters: [0]=cand cnt, [4]=fg filt, [5]=bg filt, [1,2,8..12]=meta published by k_gather b0

// ---- threefry2x32 (exact JAX semantics) ----
__host__ __device__ inline void tf2x32(uint32_t k0, uint32_t k1, uint32_t c0, uint32_t c1,
                                       uint32_t& o0, uint32_t& o1) {
  uint32_t ks[3] = {k0, k1, k0 ^ k1 ^ 0x1BD11BDAu};
  uint32_t x0 = c0 + ks[0];
  uint32_t x1 = c1 + ks[1];
  const int rot[2][4] = {{13, 15, 26, 6}, {17, 29, 16, 24}};
#pragma unroll
  for (int i = 0; i < 5; ++i) {
#pragma unroll
    for (int j = 0; j < 4; ++j) {
      x0 += x1;
      int r = rot[i & 1][j];
      x1 = (x1 << r) | (x1 >> (32 - r));
      x1 ^= x0;
    }
    x0 += ks[(i + 1) % 3];
    x1 += ks[(i + 2) % 3] + (uint32_t)(i + 1);
  }
  o0 = x0; o1 = x1;
}

// Partitionable threefry: element i uses block (0,i); draw = o0^o1.
// Selection key = (bits>>9, index) lexicographic (stable argsort tiebreak).
__device__ inline uint64_t sel_key(uint32_t i, uint32_t ka, uint32_t kb) {
  uint32_t o0, o1;
  tf2x32(ka, kb, 0u, i, o0, o1);
  uint32_t bits = o0 ^ o1;
  return ((uint64_t)(bits >> 9) << 32) | (uint64_t)i;
}

__device__ inline uint32_t fmap(float v) {
  uint32_t u = __float_as_uint(v);
  return (u & 0x80000000u) ? ~u : (u | 0x80000000u);
}
__device__ inline float funmap(uint32_t m) {
  return (m & 0x80000000u) ? __uint_as_float(m & 0x7FFFFFFFu) : __uint_as_float(~m);
}

// wave-64 max via 6 DPP steps; exact result in lane 63. Values >= 0 or NaN;
// bound_ctrl 0-fill and NaN-drop by v_max are harmless here (see R7 analysis).
__device__ inline float wave_max_dpp(float v) {
  int x;
  x = __builtin_amdgcn_mov_dpp(__float_as_int(v), 0xB1, 0xF, 0xF, true);   // quad_perm 1,0,3,2
  v = fmaxf(v, __int_as_float(x));
  x = __builtin_amdgcn_mov_dpp(__float_as_int(v), 0x4E, 0xF, 0xF, true);   // quad_perm 2,3,0,1
  v = fmaxf(v, __int_as_float(x));
  x = __builtin_amdgcn_mov_dpp(__float_as_int(v), 0x114, 0xF, 0xF, true);  // row_shr:4
  v = fmaxf(v, __int_as_float(x));
  x = __builtin_amdgcn_mov_dpp(__float_as_int(v), 0x118, 0xF, 0xF, true);  // row_shr:8
  v = fmaxf(v, __int_as_float(x));
  x = __builtin_amdgcn_mov_dpp(__float_as_int(v), 0x142, 0xF, 0xF, true);  // row_bcast:15
  v = fmaxf(v, __int_as_float(x));
  x = __builtin_amdgcn_mov_dpp(__float_as_int(v), 0x143, 0xF, 0xF, true);  // row_bcast:31
  v = fmaxf(v, __int_as_float(x));
  return v;
}

// Single IoU pass; per-gt wave max via DPP chain (no LDS in hot loop), per-lane
// register accumulator part2[s] holding g = s*64+lane. Small LDS -> high occupancy.
__global__ void __launch_bounds__(256)
k_main(const float4* __restrict__ anc, const float* __restrict__ img,
       const float4* __restrict__ gt, int N, int R,
       uint32_t* __restrict__ pmax, uint32_t* __restrict__ gmaxu,
       float* __restrict__ LBL, float4* __restrict__ TGT,
       uint32_t* __restrict__ pmeta) {
  __shared__ float4 sgt[NGT_MAX];
  __shared__ float sarea[NGT_MAX];
  __shared__ float swv[4 * 104];  // [wave][g]
  __shared__ uint32_t scnt[2];
  const int t = threadIdx.x;
  const int b = blockIdx.x;
  if (t < 2) scnt[t] = 0u;
  if (t < R) {
    float4 g = gt[t];
    sgt[t] = g;
    {
#pragma clang fp contract(off)
      sarea[t] = (g.z - g.x + 1.0f) * (g.w - g.y + 1.0f);
    }
  }
  __syncthreads();
  const int lane = t & 63, wid = t >> 6;
  const int i = b * 256 + t;  // N multiple of 256
  const float H = img[0], W = img[1];
  float4 a = anc[i];
  bool inside = (a.x >= 0.0f) && (a.y >= 0.0f) && (a.z < W) && (a.w < H);
  float area_a;
  {
#pragma clang fp contract(off)
    area_a = (a.z - a.x + 1.0f) * (a.w - a.y + 1.0f);
  }
  if (!inside) area_a = __uint_as_float(0x7FC00000u);  // NaN-poison; v_max drops NaN
  float part2[2] = {-1.0f, -1.0f};
  float vmax = -1.0f;
#pragma unroll 4
  for (int g = 0; g < R; ++g) {
    float4 gb = sgt[g];
    float v;
    {
#pragma clang fp contract(off)
      float iw = fminf(a.z, gb.z) - fmaxf(a.x, gb.x) + 1.0f;
      float ih = fminf(a.w, gb.w) - fmaxf(a.y, gb.y) + 1.0f;
      float inter = fmaxf(iw, 0.0f) * fmaxf(ih, 0.0f);
      v = inter / (area_a + sarea[g] - inter);
    }
    vmax = fmaxf(vmax, v);
    float wm = wave_max_dpp(v);
    float rl = __int_as_float(__builtin_amdgcn_readlane(__float_as_int(wm), 63));
    if (lane == (g & 63)) part2[g >> 6] = rl;
  }
  float lbl = -1.0f;
  if (inside) {
    if (vmax < 0.3f) lbl = 0.0f;
    if (vmax >= 0.7f) lbl = 1.0f;
  }
  LBL[i] = lbl;
  unsigned long long bf = __ballot(lbl == 1.0f);
  unsigned long long bb = __ballot(lbl == 0.0f);
  if (lane == 0) {
    atomicAdd(&scnt[0], (uint32_t)__popcll(bf));
    atomicAdd(&scnt[1], (uint32_t)__popcll(bb));
  }
  float4 o = make_float4(0.f, 0.f, 0.f, 0.f);
  if (inside) {
    int idx = (int)vmax;  // faithful astype(int32) of max_ov
    idx = idx < 0 ? 0 : idx;
    idx = idx > R - 1 ? R - 1 : idx;
    float4 gb = sgt[idx];
    {
#pragma clang fp contract(off)
      float aw = a.z - a.x + 1.0f;
      float ah = a.w - a.y + 1.0f;
      float acx = a.x + 0.5f * aw;
      float acy = a.y + 0.5f * ah;
      float gw = gb.z - gb.x + 1.0f;
      float gh = gb.w - gb.y + 1.0f;
      float gcx = gb.x + 0.5f * gw;
      float gcy = gb.y + 0.5f * gh;
      o.x = (gcx - acx) / aw;
      o.y = (gcy - acy) / ah;
      o.z = logf(gw / aw);
      o.w = logf(gh / ah);
    }
  }
  TGT[i] = o;
  // epilogue: 1-2 LDS writes per lane, then 4-deep per-gt reduction
  if (lane < R) swv[wid * 104 + lane] = part2[0];
  if (64 + lane < R) swv[wid * 104 + 64 + lane] = part2[1];
  __syncthreads();
  if (t < R) {
    float m = fmaxf(fmaxf(swv[t], swv[104 + t]), fmaxf(swv[208 + t], swv[312 + t]));
    uint32_t u = fmap(m);
    pmax[b * R + t] = u;
    if (u > gmaxu[t]) atomicMax(&gmaxu[t], u);  // stale-high skip safe (monotone)
  }
  if (t == 0) pmeta[b] = scnt[0] | (scnt[1] << 16);
}

// Tie-set candidates + snapshot of their pre-flip labels. Block-staged append.
__global__ void __launch_bounds__(256)
k_cand(const float4* __restrict__ anc, const float* __restrict__ img,
       const float4* __restrict__ gt, int N, int R,
       const uint32_t* __restrict__ pmax, const uint32_t* __restrict__ gmaxu,
       const float* __restrict__ LBL,
       uint64_t* __restrict__ candList, uint32_t* __restrict__ candLbl,
       uint32_t* __restrict__ counters, uint32_t ka, uint32_t kb) {
  __shared__ int tg[NGT_MAX];
  __shared__ float tgm[NGT_MAX];
  __shared__ uint64_t buf[256];
  __shared__ uint32_t bufL[256];
  __shared__ uint32_t bcnt, bbase;
  __shared__ int tcnt;
  const int t = threadIdx.x, b = blockIdx.x;
  if (t == 0) { tcnt = 0; bcnt = 0u; }
  __syncthreads();
  if (t < R) {
    uint32_t pm = pmax[b * R + t];
    uint32_t gm = gmaxu[t];
    if (pm == gm) { int p = atomicAdd(&tcnt, 1); tg[p] = t; tgm[p] = funmap(gm); }
  }
  __syncthreads();
  const int C0 = tcnt;
  if (C0 == 0) return;
  const int i = b * 256 + t;
  const float H = img[0], W = img[1];
  float4 a = anc[i];
  bool inside = (a.x >= 0.0f) && (a.y >= 0.0f) && (a.z < W) && (a.w < H);
  if (inside) {
    float area_a;
    {
#pragma clang fp contract(off)
      area_a = (a.z - a.x + 1.0f) * (a.w - a.y + 1.0f);
    }
    bool cand = false;
    for (int j = 0; j < C0; ++j) {
      float4 gb = gt[tg[j]];
      float v;
      {
#pragma clang fp contract(off)
        float ag = (gb.z - gb.x + 1.0f) * (gb.w - gb.y + 1.0f);
        float iw = fminf(a.z, gb.z) - fmaxf(a.x, gb.x) + 1.0f;
        float ih = fminf(a.w, gb.w) - fmaxf(a.y, gb.y) + 1.0f;
        float inter = fmaxf(iw, 0.0f) * fmaxf(ih, 0.0f);
        v = inter / (area_a + ag - inter);
      }
      cand = cand || (v == tgm[j]);
    }
    if (cand) {
      float old = LBL[i];
      uint32_t code = (old == 1.0f) ? 2u : ((old == 0.0f) ? 1u : 0u);
      uint32_t p = atomicAdd(&bcnt, 1u);
      buf[p] = sel_key((uint32_t)i, ka, kb);
      bufL[p] = code;
    }
  }
  __syncthreads();
  if (t == 0 && bcnt) bbase = atomicAdd(&counters[0], bcnt);
  __syncthreads();
  for (uint32_t j = t; j < bcnt; j += 256) {
    uint32_t p = bbase + j;
    if (p < CAND_CAP) { candList[p] = buf[j]; candLbl[p] = bufL[j]; }
  }
}

// Merged meta+gather: per-block recompute of M1/M2 + kept-cand set + thresholds;
// applies flips + prefilter; block-staged appends. Block 0 publishes meta for k_sel.
__global__ void __launch_bounds__(256)
k_gather(float* __restrict__ LBL, int N, int NB, int R,
         const uint64_t* __restrict__ candList, const uint32_t* __restrict__ candLbl,
         const uint32_t* __restrict__ pmeta,
         uint64_t* __restrict__ listF, uint64_t* __restrict__ listB,
         uint32_t* __restrict__ counters,
         uint32_t k2a, uint32_t k2b, uint32_t k3a, uint32_t k3b) {
  __shared__ uint64_t sub[RANK_CAP];
  __shared__ uint64_t red[256];
  __shared__ uint64_t bufF[256], bufB[256];
  __shared__ uint32_t sflag[256];
  __shared__ uint32_t sdFB[2];
  __shared__ uint32_t smeta[6];
  __shared__ uint32_t cF, cB, oF, oB;
  const int t = threadIdx.x, b = blockIdx.x;
  sflag[t] = 0u;
  if (t < 2) sdFB[t] = 0u;
  if (t == 0) { cF = 0u; cB = 0u; }
  uint64_t sm = 0;
  for (int j = t; j < NB; j += 256) {
    uint32_t v = pmeta[j];
    sm += (uint64_t)(v & 0xFFFFu) | ((uint64_t)(v >> 16) << 32);
  }
  red[t] = sm;
  uint32_t C = counters[0];
  if (C > RANK_CAP) C = RANK_CAP;
  __syncthreads();
  for (int s = 128; s > 0; s >>= 1) {
    if (t < s) red[t] += red[t + s];
    __syncthreads();
  }
  const uint32_t baseF = (uint32_t)(red[0] & 0xFFFFFFFFu);
  const uint32_t baseB = (uint32_t)(red[0] >> 32);
  for (uint32_t s = t; s < C; s += 256) sub[s] = candList[s];
  __syncthreads();
  for (uint32_t e = t; e < C; e += 256) {
    uint64_t key = sub[e];
    bool keep = true;
    if (C > (uint32_t)R) {
      uint32_t rank = 0;
      for (uint32_t j = 0; j < C; ++j) rank += (sub[j] < key) ? 1u : 0u;
      keep = (rank < (uint32_t)R);
    }
    if (keep) {
      uint32_t code = candLbl[e];
      if (code != 2u) atomicAdd(&sdFB[0], 1u);
      if (code == 1u) atomicAdd(&sdFB[1], 1u);
      uint32_t idx = (uint32_t)key;
      if ((int)(idx >> 8) == b) sflag[idx & 255u] = 1u;
    }
  }
  __syncthreads();
  if (t == 0) {
    uint32_t M1 = baseF + sdFB[0];
    uint32_t M2 = baseB - sdFB[1];
    uint32_t nfg = M1 < 128u ? M1 : 128u;
    uint32_t kbg = 256u - nfg;
    uint32_t needF = (M1 > 128u) ? 1u : 0u;
    uint32_t needB = (M2 > kbg) ? 1u : 0u;
    uint64_t Tf = 0, Tb = 0;
    if (needF) {
      Tf = (((uint64_t)(128u * 32u)) << 23) / (uint64_t)M1;
      if (Tf > (1u << 23)) Tf = (1u << 23);
    }
    if (needB) {
      Tb = (((uint64_t)(kbg * 32u)) << 23) / (uint64_t)M2;
      if (Tb > (1u << 23)) Tb = (1u << 23);
    }
    smeta[0] = needF; smeta[1] = needB; smeta[2] = (uint32_t)Tf; smeta[3] = (uint32_t)Tb;
    if (b == 0) {
      counters[1] = M1; counters[2] = M2;
      counters[8] = needF; counters[9] = needB;
      counters[10] = (uint32_t)Tf; counters[11] = (uint32_t)Tb;
      counters[12] = kbg;
    }
  }
  __syncthreads();
  const uint32_t needF = smeta[0], needB = smeta[1], Tf = smeta[2], Tb = smeta[3];
  const int i = b * 256 + t;
  float old = LBL[i];
  float l1 = sflag[t] ? 1.0f : old;
  float out = l1;
  if (l1 == 1.0f) {
    if (needF) {
      uint64_t key = sel_key((uint32_t)i, k2a, k2b);
      if ((uint32_t)(key >> 32) >= Tf) {
        out = -1.0f;  // provably not among the k smallest
      } else {
        uint32_t p = atomicAdd(&cF, 1u);
        bufF[p] = key;
      }
    }
  } else if (l1 == 0.0f) {
    if (needB) {
      uint64_t key = sel_key((uint32_t)i, k3a, k3b);
      if ((uint32_t)(key >> 32) >= Tb) {
        out = -1.0f;
      } else {
        uint32_t p = atomicAdd(&cB, 1u);
        bufB[p] = key;
      }
    }
  }
  LBL[i] = out;
  __syncthreads();
  if (t == 0 && cF) oF = atomicAdd(&counters[4], cF);
  if (t == 64 && cB) oB = atomicAdd(&counters[5], cB);
  __syncthreads();
  for (uint32_t j = t; j < cF; j += 256) {
    uint32_t p = oF + j;
    if (p < FILT_CAP) listF[p] = bufF[j];
  }
  for (uint32_t j = t; j < cB; j += 256) {
    uint32_t p = oB + j;
    if (p < FILT_CAP) listB[p] = bufB[j];
  }
}

// exact k-smallest among filtered list (all keys < T): 256-bin hist + scan + in-bin rank.
__device__ __forceinline__ void do_select(const uint64_t* list, uint32_t Mf, uint32_t k,
                                          uint32_t T, float* LBL, uint32_t* h,
                                          uint32_t* c0, uint32_t* c1, uint64_t* sub,
                                          uint32_t* scal) {
  const int t = threadIdx.x;
  if (Mf <= k) return;  // keep all (uniform)
  int bl = (T > 1u) ? (32 - __clz(T - 1u)) : 0;
  int shift = bl > 8 ? bl - 8 : 0;
  h[t] = 0u;
  if (t == 0) { scal[0] = 0u; scal[1] = 0u; scal[2] = 0u; }
  __syncthreads();
  for (uint32_t j = t; j < Mf; j += 256)
    atomicAdd(&h[((uint32_t)(list[j] >> 32)) >> shift], 1u);
  __syncthreads();
  c0[t] = h[t];
  __syncthreads();
  uint32_t* s = c0;
  uint32_t* d = c1;
  for (int dd = 1; dd < 256; dd <<= 1) {
    uint32_t v = s[t];
    if (t >= dd) v += s[t - dd];
    d[t] = v;
    __syncthreads();
    uint32_t* tmp = s; s = d; d = tmp;
  }
  uint32_t inc = s[t];
  uint32_t exc = inc - h[t];
  if (exc < k && inc >= k) { scal[1] = (uint32_t)t; scal[2] = k - exc; }
  __syncthreads();
  const uint32_t binb = scal[1], rneed = scal[2];
  for (uint32_t j = t; j < Mf; j += 256) {
    uint64_t key = list[j];
    uint32_t bin = ((uint32_t)(key >> 32)) >> shift;
    if (bin > binb) {
      LBL[(uint32_t)key] = -1.0f;
    } else if (bin == binb) {
      uint32_t p = atomicAdd(&scal[0], 1u);
      if (p < SUB_CAP) sub[p] = key;
    }
  }
  __syncthreads();
  uint32_t c = scal[0] < SUB_CAP ? scal[0] : SUB_CAP;
  for (uint32_t s2 = t; s2 < c; s2 += 256) {
    uint64_t key = sub[s2];
    uint32_t rank = 0u;
    for (uint32_t j = 0; j < c; ++j) rank += (sub[j] < key) ? 1u : 0u;
    if (rank >= rneed) LBL[(uint32_t)key] = -1.0f;
  }
  __syncthreads();
}

__global__ void __launch_bounds__(256)
k_sel(float* __restrict__ LBL, const uint64_t* __restrict__ listF,
      const uint64_t* __restrict__ listB, uint32_t* __restrict__ counters) {
  __shared__ uint32_t h[256], c0[256], c1[256];
  __shared__ uint64_t sub[SUB_CAP];
  __shared__ uint32_t scal[4];
  if (counters[8]) {
    uint32_t Mf = counters[4];
    if (Mf > FILT_CAP) Mf = FILT_CAP;
    do_select(listF, Mf, 128u, counters[10], LBL, h, c0, c1, sub, scal);
  }
  if (counters[9]) {
    uint32_t Mf = counters[5];
    if (Mf > FILT_CAP) Mf = FILT_CAP;
    do_select(listB, Mf, counters[12], counters[11], LBL, h, c0, c1, sub, scal);
  }
}

extern "C" void kernel_launch(void* const* d_in, const int* in_sizes, int n_in,
                              void* d_out, int out_size, void* d_ws, size_t ws_size,
                              hipStream_t stream) {
  (void)n_in; (void)out_size; (void)ws_size;
  const int N = in_sizes[0] / 4;  // 262144 anchors (multiple of 256)
  const int R = in_sizes[2] / 4;  // 100 gt boxes
  const int NB = N / 256;
  const float4* anc = (const float4*)d_in[0];
  const float* img = (const float*)d_in[1];
  const float4* gtb = (const float4*)d_in[2];
  float* LBL = (float*)d_out;
  float4* TGT = (float4*)((float*)d_out + N);

  uint8_t* ws = (uint8_t*)d_ws;
  uint32_t* counters = (uint32_t*)ws;                  // 16 u32 @ 0
  uint32_t* gmaxu = (uint32_t*)(ws + 512);             // 128 u32 @ 512
  uint32_t* pmeta = (uint32_t*)(ws + 1024);            // NB u32 @ 1024
  uint32_t* candLbl = (uint32_t*)(ws + 1024 + 4096);   // CAND_CAP u32
  uint32_t* pmax = (uint32_t*)(ws + 65536);            // NB*R u32 (~410 KB)
  size_t off = 65536 + (size_t)NB * R * 4;
  off = (off + 7) & ~(size_t)7;
  uint64_t* candList = (uint64_t*)(ws + off);
  uint64_t* listF = (uint64_t*)(ws + off + CAND_CAP * 8);
  uint64_t* listB = (uint64_t*)(ws + off + CAND_CAP * 8 + FILT_CAP * 8);

  // Partitionable jax.random.split(key(42), 3): key_j = threefry((0,42),(0,j))
  uint32_t k1a, k1b, k2a, k2b, k3a, k3b;
  tf2x32(0u, 42u, 0u, 0u, k1a, k1b);
  tf2x32(0u, 42u, 0u, 1u, k2a, k2b);
  tf2x32(0u, 42u, 0u, 2u, k3a, k3b);

  hipMemsetAsync(ws, 0, 1024, stream);  // counters + gmaxu
  k_main<<<NB, 256, 0, stream>>>(anc, img, gtb, N, R, pmax, gmaxu, LBL, TGT, pmeta);
  k_cand<<<NB, 256, 0, stream>>>(anc, img, gtb, N, R, pmax, gmaxu, LBL, candList, candLbl,
                                 counters, k1a, k1b);
  k_gather<<<NB, 256, 0, stream>>>(LBL, N, NB, R, candList, candLbl, pmeta, listF, listB,
                                   counters, k2a, k2b, k3a, k3b);
  k_sel<<<1, 256, 0, stream>>>(LBL, listF, listB, counters);
}